// Round 7
// baseline (283.580 us; speedup 1.0000x reference)
//
#include <hip/hip_runtime.h>
#include <math.h>

// out[b] = dot(state[b], E[idx[b]]) - logsumexp_n dot(state[b], E[n])
// B=2048, D=64, N=100000, T=1.0
//
// Round-7: same MFMA split-precision structure as r6 (S=Sh+Sl, E=Eh+El,
// 3 passes), but latency-engineered (r6 evidence: MfmaUtil 16%, VGPR=36
// -> zero prefetch, depth-6 MFMA chains, 16 waves/CU):
//  - explicit double-buffered B-tile prefetch (named X/Y register bufs)
//  - 4 independent MFMA chains per tile (depth 4 + depth 2 per c-tile)
//  - 128 chunks -> 2048 blocks (8/CU feed), launch_bounds(256,4)
// State pre-scaled by log2e; no online max (|logit·log2e| < 128, fp32-safe).

typedef short short8 __attribute__((ext_vector_type(8)));
typedef float f32x4 __attribute__((ext_vector_type(4)));

constexpr int kD = 64;
constexpr int kChunks = 128;
constexpr int kChunkItems = 784;    // 49 tiles; last chunk 432 = 27 tiles
constexpr float kLog2e = 1.44269504088896340736f;

static __device__ inline unsigned short bf16_rne(float x) {
    unsigned int u = __builtin_bit_cast(unsigned int, x);
    u = (u + 0x7FFFu + ((u >> 16) & 1u)) >> 16;
    return (unsigned short)u;
}
static __device__ inline float bf16_f32(unsigned short h) {
    unsigned int u = ((unsigned int)h) << 16;
    return __builtin_bit_cast(float, u);
}

__global__ __launch_bounds__(256) void prep_e_kernel(
    const float* __restrict__ src, unsigned short* __restrict__ hi,
    unsigned short* __restrict__ lo, int total4, float scale)
{
    int i = blockIdx.x * 256 + threadIdx.x;
    if (i >= total4) return;
    float4 v = ((const float4*)src)[i];
    v.x *= scale; v.y *= scale; v.z *= scale; v.w *= scale;
    ushort4 h, l;
    h.x = bf16_rne(v.x); l.x = bf16_rne(v.x - bf16_f32(h.x));
    h.y = bf16_rne(v.y); l.y = bf16_rne(v.y - bf16_f32(h.y));
    h.z = bf16_rne(v.z); l.z = bf16_rne(v.z - bf16_f32(h.z));
    h.w = bf16_rne(v.w); l.w = bf16_rne(v.w - bf16_f32(h.w));
    ((ushort4*)hi)[i] = h;
    ((ushort4*)lo)[i] = l;
}

#define MFMA16(a, b, c) __builtin_amdgcn_mfma_f32_16x16x32_bf16((a), (b), (c), 0, 0, 0)

__global__ __launch_bounds__(256, 4) void lse_mfma_kernel(
    const unsigned short* __restrict__ Sh,  // [B][64] bf16, pre-scaled log2e
    const unsigned short* __restrict__ Sl,
    const unsigned short* __restrict__ Eh,  // [N][64] bf16
    const unsigned short* __restrict__ El,
    float* __restrict__ part,               // [B][kChunks] exp2-sums
    int N)
{
    const int wave = threadIdx.x >> 6;
    const int lane = threadIdx.x & 63;
    const int l15  = lane & 15;
    const int lhi  = lane >> 4;
    const int chunk = blockIdx.x;                 // 0..127
    const int rowg  = blockIdx.y;                 // 0..15
    const int r0 = rowg * 128 + wave * 32;        // wave's first state row

    const int n0 = chunk * kChunkItems;
    const int cnt = min(kChunkItems, N - n0);
    const int ntiles = cnt >> 4;                  // 49 or 27, all full tiles

    // A fragments: [rowtile][hi/lo][kstep]
    short8 A[2][2][2];
    #pragma unroll
    for (int rt = 0; rt < 2; ++rt) {
        const int row = r0 + rt * 16 + l15;
        const size_t base = (size_t)row * kD + lhi * 8;
        A[rt][0][0] = *(const short8*)(Sh + base);
        A[rt][0][1] = *(const short8*)(Sh + base + 32);
        A[rt][1][0] = *(const short8*)(Sl + base);
        A[rt][1][1] = *(const short8*)(Sl + base + 32);
    }

    float acc[2][4];
    #pragma unroll
    for (int rt = 0; rt < 2; ++rt)
        #pragma unroll
        for (int j = 0; j < 4; ++j) acc[rt][j] = 0.f;

    const int voff = l15 * kD + lhi * 8;
    const unsigned short* eh = Eh + (size_t)n0 * kD + voff;
    const unsigned short* el = El + (size_t)n0 * kD + voff;
    // tile stride = 16 items * 64 dims = 1024 elements

    short8 Xh0, Xh1, Xl0, Xl1;   // buffer X
    short8 Yh0, Yh1, Yl0, Yl1;   // buffer Y

#define LOAD_X(t) { const size_t o_ = (size_t)(t) * 1024; \
    Xh0 = *(const short8*)(eh + o_);      Xh1 = *(const short8*)(eh + o_ + 32); \
    Xl0 = *(const short8*)(el + o_);      Xl1 = *(const short8*)(el + o_ + 32); }
#define LOAD_Y(t) { const size_t o_ = (size_t)(t) * 1024; \
    Yh0 = *(const short8*)(eh + o_);      Yh1 = *(const short8*)(eh + o_ + 32); \
    Yl0 = *(const short8*)(el + o_);      Yl1 = *(const short8*)(el + o_ + 32); }

    // 4 independent chains: c{0,1}a = Sh*Eh then Sh*El (depth 4),
    //                       c{0,1}b = Sl*Eh (depth 2)
#define COMP(h0, h1, l0, l1) { \
    const f32x4 z_ = {0.f, 0.f, 0.f, 0.f}; \
    f32x4 c0a = MFMA16(A[0][0][0], h0, z_); \
    f32x4 c1a = MFMA16(A[1][0][0], h0, z_); \
    f32x4 c0b = MFMA16(A[0][1][0], h0, z_); \
    f32x4 c1b = MFMA16(A[1][1][0], h0, z_); \
    c0a = MFMA16(A[0][0][1], h1, c0a); \
    c1a = MFMA16(A[1][0][1], h1, c1a); \
    c0b = MFMA16(A[0][1][1], h1, c0b); \
    c1b = MFMA16(A[1][1][1], h1, c1b); \
    c0a = MFMA16(A[0][0][0], l0, c0a); \
    c1a = MFMA16(A[1][0][0], l0, c1a); \
    c0a = MFMA16(A[0][0][1], l1, c0a); \
    c1a = MFMA16(A[1][0][1], l1, c1a); \
    _Pragma("unroll") \
    for (int j = 0; j < 4; ++j) { \
        acc[0][j] += __builtin_amdgcn_exp2f(c0a[j] + c0b[j]); \
        acc[1][j] += __builtin_amdgcn_exp2f(c1a[j] + c1b[j]); \
    } }

    LOAD_X(0);
    int t = 0;
    for (; t + 2 <= ntiles; t += 2) {
        LOAD_Y(t + 1);
        COMP(Xh0, Xh1, Xl0, Xl1);
        if (t + 2 < ntiles) LOAD_X(t + 2);
        COMP(Yh0, Yh1, Yl0, Yl1);
    }
    if (t < ntiles) COMP(Xh0, Xh1, Xl0, Xl1);   // odd-count tail (in X)

#undef LOAD_X
#undef LOAD_Y
#undef COMP

    // Reduce the 16 column-residues (lanes sharing lhi) per row; write part.
    // C layout: col = lane&15, row = (lane>>4)*4 + j.
    #pragma unroll
    for (int rt = 0; rt < 2; ++rt) {
        #pragma unroll
        for (int j = 0; j < 4; ++j) {
            float v = acc[rt][j];
            v += __shfl_xor(v, 1, 64);
            v += __shfl_xor(v, 2, 64);
            v += __shfl_xor(v, 4, 64);
            v += __shfl_xor(v, 8, 64);
            if (l15 == 0) {
                const int row = r0 + rt * 16 + lhi * 4 + j;
                part[(size_t)row * kChunks + chunk] = v;
            }
        }
    }
}

__global__ __launch_bounds__(256) void finalize_kernel(
    const float* __restrict__ state,   // original fp32
    const float* __restrict__ emb,
    const int* __restrict__ idx,
    const float* __restrict__ part,    // [B][kChunks]
    float* __restrict__ out)
{
    const int wave = threadIdx.x >> 6;
    const int lane = threadIdx.x & 63;
    const int row  = blockIdx.x * 4 + wave;

    // Sum 128 chunk partials (2 per lane). part holds sums of e^logit.
    const float* pr = part + (size_t)row * kChunks;
    float sv = pr[lane] + pr[lane + 64];
    #pragma unroll
    for (int o = 32; o; o >>= 1) sv += __shfl_xor(sv, o, 64);
    float lse = logf(sv);

    // Selected-item logit in fp32: lane k holds dim k.
    int id = idx[row];
    float d = state[(size_t)row * kD + lane] * emb[(size_t)id * kD + lane];
    #pragma unroll
    for (int o = 32; o; o >>= 1) d += __shfl_xor(d, o, 64);

    if (lane == 0) out[row] = d - lse;
}

extern "C" void kernel_launch(void* const* d_in, const int* in_sizes, int n_in,
                              void* d_out, int out_size, void* d_ws, size_t ws_size,
                              hipStream_t stream) {
    const float* state = (const float*)d_in[0];       // [B, 64]
    const int*   idx   = (const int*)d_in[1];         // [B]
    const float* emb   = (const float*)d_in[2];       // [N, 64]
    float*       out   = (float*)d_out;               // [B]

    const int B = in_sizes[0] / kD;                   // 2048
    const int N = in_sizes[2] / kD;                   // 100000

    // Workspace layout (16B-aligned):
    char* ws = (char*)d_ws;
    size_t szE = (size_t)N * kD * sizeof(unsigned short);     // 12.8 MB
    size_t szS = (size_t)B * kD * sizeof(unsigned short);     // 256 KB
    unsigned short* Eh = (unsigned short*)ws;                  ws += szE;
    unsigned short* El = (unsigned short*)ws;                  ws += szE;
    unsigned short* Sh = (unsigned short*)ws;                  ws += szS;
    unsigned short* Sl = (unsigned short*)ws;                  ws += szS;
    float* part = (float*)ws;                                  // B*128*4 = 1 MB

    // Convert E -> bf16 hi/lo (unscaled); S -> bf16 hi/lo scaled by log2e.
    int e4 = N * kD / 4;
    prep_e_kernel<<<(e4 + 255) / 256, 256, 0, stream>>>(emb, Eh, El, e4, 1.0f);
    int s4 = B * kD / 4;
    prep_e_kernel<<<(s4 + 255) / 256, 256, 0, stream>>>(state, Sh, Sl, s4, kLog2e);

    dim3 grid(kChunks, B / 128);                      // (128, 16) = 2048 blocks
    lse_mfma_kernel<<<grid, 256, 0, stream>>>(Sh, Sl, Eh, El, part, N);

    finalize_kernel<<<B / 4, 256, 0, stream>>>(state, emb, idx, part, out);
}

// Round 8
// 279.287 us; speedup vs baseline: 1.0154x; 1.0154x over previous
//
#include <hip/hip_runtime.h>
#include <math.h>

// out[b] = dot(state[b], E[idx[b]]) - logsumexp_n dot(state[b], E[n])
// B=2048, D=64, N=100000, T=1.0
//
// Round-8: r6's simple MFMA loop (split precision: S=Sh+Sl, E=Eh+El,
// 3 passes) with ONE main lever: occupancy. r6 evidence: 1024 blocks =
// 4/CU = 16 waves/CU, MfmaUtil 16%; structural caps (MFMA pipe, L1/L2 BW)
// all allow >>50%, so the kernel is TLP-starved. Now 2048 blocks =
// 8 blocks/CU = 32 waves/CU (VGPR ~44 <= 64 so 8 waves/SIMD fit).
// No manual prefetch, no launch_bounds min-waves (r7 post-mortem: both
// regressed -- compiler defeats source pipelining, Common-mistake #5).
// part[] transposed to [chunk][row]: contiguous block writes (r6/r7
// showed 4-9 MB WRITE_SIZE from 64B-line write-amp on strided writes).
// State pre-scaled by log2e; no online max (|logit·log2e| < 128, fp32-safe).

typedef short short8 __attribute__((ext_vector_type(8)));
typedef float f32x4 __attribute__((ext_vector_type(4)));

constexpr int kD = 64;
constexpr int kChunks = 128;
constexpr int kChunkItems = 784;    // 49 tiles; last chunk 432 = 27 tiles
constexpr float kLog2e = 1.44269504088896340736f;

static __device__ inline unsigned short bf16_rne(float x) {
    unsigned int u = __builtin_bit_cast(unsigned int, x);
    u = (u + 0x7FFFu + ((u >> 16) & 1u)) >> 16;
    return (unsigned short)u;
}
static __device__ inline float bf16_f32(unsigned short h) {
    unsigned int u = ((unsigned int)h) << 16;
    return __builtin_bit_cast(float, u);
}

__global__ __launch_bounds__(256) void prep_e_kernel(
    const float* __restrict__ src, unsigned short* __restrict__ hi,
    unsigned short* __restrict__ lo, int total4, float scale)
{
    int i = blockIdx.x * 256 + threadIdx.x;
    if (i >= total4) return;
    float4 v = ((const float4*)src)[i];
    v.x *= scale; v.y *= scale; v.z *= scale; v.w *= scale;
    ushort4 h, l;
    h.x = bf16_rne(v.x); l.x = bf16_rne(v.x - bf16_f32(h.x));
    h.y = bf16_rne(v.y); l.y = bf16_rne(v.y - bf16_f32(h.y));
    h.z = bf16_rne(v.z); l.z = bf16_rne(v.z - bf16_f32(h.z));
    h.w = bf16_rne(v.w); l.w = bf16_rne(v.w - bf16_f32(h.w));
    ((ushort4*)hi)[i] = h;
    ((ushort4*)lo)[i] = l;
}

#define MFMA16(a, b, c) __builtin_amdgcn_mfma_f32_16x16x32_bf16((a), (b), (c), 0, 0, 0)

__global__ __launch_bounds__(256) void lse_mfma_kernel(
    const unsigned short* __restrict__ Sh,  // [B][64] bf16, pre-scaled log2e
    const unsigned short* __restrict__ Sl,
    const unsigned short* __restrict__ Eh,  // [N][64] bf16
    const unsigned short* __restrict__ El,
    float* __restrict__ part,               // [kChunks][B] exp2-sums
    int N, int Btot)
{
    const int wave = threadIdx.x >> 6;
    const int lane = threadIdx.x & 63;
    const int l15  = lane & 15;
    const int lhi  = lane >> 4;
    const int chunk = blockIdx.x;                 // 0..127
    const int rowg  = blockIdx.y;                 // 0..15
    const int r0 = rowg * 128 + wave * 32;        // wave's first state row

    const int n0 = chunk * kChunkItems;
    const int cnt = min(kChunkItems, N - n0);
    const int ntiles = cnt >> 4;                  // 49 or 27, all full tiles

    // A fragments: [rowtile][hi/lo][kstep]
    short8 A[2][2][2];
    #pragma unroll
    for (int rt = 0; rt < 2; ++rt) {
        const int row = r0 + rt * 16 + l15;
        const size_t base = (size_t)row * kD + lhi * 8;
        A[rt][0][0] = *(const short8*)(Sh + base);
        A[rt][0][1] = *(const short8*)(Sh + base + 32);
        A[rt][1][0] = *(const short8*)(Sl + base);
        A[rt][1][1] = *(const short8*)(Sl + base + 32);
    }

    float acc[2][4];
    #pragma unroll
    for (int rt = 0; rt < 2; ++rt)
        #pragma unroll
        for (int j = 0; j < 4; ++j) acc[rt][j] = 0.f;

    const int voff = l15 * kD + lhi * 8;
    const unsigned short* eh = Eh + (size_t)n0 * kD + voff;
    const unsigned short* el = El + (size_t)n0 * kD + voff;

    for (int t = 0; t < ntiles; ++t) {
        const size_t o = (size_t)t * 1024;        // 16 items * 64 dims
        short8 Bh0 = *(const short8*)(eh + o);
        short8 Bh1 = *(const short8*)(eh + o + 32);
        short8 Bl0 = *(const short8*)(el + o);
        short8 Bl1 = *(const short8*)(el + o + 32);

        // 4 independent chains: c{0,1}a = Sh*Eh + Sh*El (depth 4),
        //                       c{0,1}b = Sl*Eh (depth 2)
        const f32x4 z = {0.f, 0.f, 0.f, 0.f};
        f32x4 c0a = MFMA16(A[0][0][0], Bh0, z);
        f32x4 c1a = MFMA16(A[1][0][0], Bh0, z);
        f32x4 c0b = MFMA16(A[0][1][0], Bh0, z);
        f32x4 c1b = MFMA16(A[1][1][0], Bh0, z);
        c0a = MFMA16(A[0][0][1], Bh1, c0a);
        c1a = MFMA16(A[1][0][1], Bh1, c1a);
        c0b = MFMA16(A[0][1][1], Bh1, c0b);
        c1b = MFMA16(A[1][1][1], Bh1, c1b);
        c0a = MFMA16(A[0][0][0], Bl0, c0a);
        c1a = MFMA16(A[1][0][0], Bl0, c1a);
        c0a = MFMA16(A[0][0][1], Bl1, c0a);
        c1a = MFMA16(A[1][0][1], Bl1, c1a);

        // C layout: col = lane&15, row = (lane>>4)*4 + j. Accumulate exp2.
        #pragma unroll
        for (int j = 0; j < 4; ++j) {
            acc[0][j] += __builtin_amdgcn_exp2f(c0a[j] + c0b[j]);
            acc[1][j] += __builtin_amdgcn_exp2f(c1a[j] + c1b[j]);
        }
    }

    // Reduce the 16 column-residues (lanes sharing lhi) per row.
    // part layout [chunk][row]: each block writes 128 contiguous floats.
    #pragma unroll
    for (int rt = 0; rt < 2; ++rt) {
        #pragma unroll
        for (int j = 0; j < 4; ++j) {
            float v = acc[rt][j];
            v += __shfl_xor(v, 1, 64);
            v += __shfl_xor(v, 2, 64);
            v += __shfl_xor(v, 4, 64);
            v += __shfl_xor(v, 8, 64);
            if (l15 == 0) {
                const int row = r0 + rt * 16 + lhi * 4 + j;
                part[(size_t)chunk * Btot + row] = v;
            }
        }
    }
}

__global__ __launch_bounds__(256) void finalize_kernel(
    const float* __restrict__ state,   // original fp32
    const float* __restrict__ emb,
    const int* __restrict__ idx,
    const float* __restrict__ part,    // [kChunks][B]
    float* __restrict__ out, int Btot)
{
    const int wave = threadIdx.x >> 6;
    const int lane = threadIdx.x & 63;
    const int row  = blockIdx.x * 4 + wave;

    // Sum 128 chunk partials (2 per lane), stride Btot between chunks.
    const float* pr = part + row;
    float sv = pr[(size_t)lane * Btot] + pr[(size_t)(lane + 64) * Btot];
    #pragma unroll
    for (int o = 32; o; o >>= 1) sv += __shfl_xor(sv, o, 64);
    float lse = logf(sv);

    // Selected-item logit in fp32: lane k holds dim k.
    int id = idx[row];
    float d = state[(size_t)row * kD + lane] * emb[(size_t)id * kD + lane];
    #pragma unroll
    for (int o = 32; o; o >>= 1) d += __shfl_xor(d, o, 64);

    if (lane == 0) out[row] = d - lse;
}

extern "C" void kernel_launch(void* const* d_in, const int* in_sizes, int n_in,
                              void* d_out, int out_size, void* d_ws, size_t ws_size,
                              hipStream_t stream) {
    const float* state = (const float*)d_in[0];       // [B, 64]
    const int*   idx   = (const int*)d_in[1];         // [B]
    const float* emb   = (const float*)d_in[2];       // [N, 64]
    float*       out   = (float*)d_out;               // [B]

    const int B = in_sizes[0] / kD;                   // 2048
    const int N = in_sizes[2] / kD;                   // 100000

    // Workspace layout (16B-aligned):
    char* ws = (char*)d_ws;
    size_t szE = (size_t)N * kD * sizeof(unsigned short);     // 12.8 MB
    size_t szS = (size_t)B * kD * sizeof(unsigned short);     // 256 KB
    unsigned short* Eh = (unsigned short*)ws;                  ws += szE;
    unsigned short* El = (unsigned short*)ws;                  ws += szE;
    unsigned short* Sh = (unsigned short*)ws;                  ws += szS;
    unsigned short* Sl = (unsigned short*)ws;                  ws += szS;
    float* part = (float*)ws;                                  // 128*B*4 = 1 MB

    // Convert E -> bf16 hi/lo (unscaled); S -> bf16 hi/lo scaled by log2e.
    int e4 = N * kD / 4;
    prep_e_kernel<<<(e4 + 255) / 256, 256, 0, stream>>>(emb, Eh, El, e4, 1.0f);
    int s4 = B * kD / 4;
    prep_e_kernel<<<(s4 + 255) / 256, 256, 0, stream>>>(state, Sh, Sl, s4, kLog2e);

    dim3 grid(kChunks, B / 128);                      // (128, 16) = 2048 blocks
    lse_mfma_kernel<<<grid, 256, 0, stream>>>(Sh, Sl, Eh, El, part, N, B);

    finalize_kernel<<<B / 4, 256, 0, stream>>>(state, emb, idx, part, out, B);
}

// Round 11
// 205.398 us; speedup vs baseline: 1.3806x; 1.3597x over previous
//
#include <hip/hip_runtime.h>
#include <math.h>

// out[b] = dot(state[b], E[idx[b]]) - logsumexp_n dot(state[b], E[n])
// B=2048, D=64, N=100000, T=1.0
//
// Round-11 = round-9 resubmitted again (broker timeouts r9, r10; never ran).
// Split-precision MFMA (S=Sh+Sl, E=Eh+El, 3 passes: hh, lh, hl).
// ONE lever vs r6: B-reuse per wave doubled. Each wave holds 64 state rows
// (A = 4 row-tiles, ~64 VGPRs); each 4 KB B-tile (16 items, Eh+El) feeds
// 24 MFMAs (116 cy) instead of 12 (58 cy) -> load:compute ratio halved,
// total tile-steps halved. Evidence: r6/r8 latency-bound at MfmaUtil
// 13-16%, not BW-bound (L1 traffic/64Bcy ~= 41 us << 237 us); more TLP
// (r8) regressed, so buy ILP-per-byte instead.
// Grid: 128 chunks x 8 rowgroups = 1024 blocks = 4/CU (r6's best).
// State pre-scaled by log2e; no online max (|logit·log2e| < 128, fp32-safe).

typedef short short8 __attribute__((ext_vector_type(8)));
typedef float f32x4 __attribute__((ext_vector_type(4)));

constexpr int kD = 64;
constexpr int kChunks = 128;
constexpr int kChunkItems = 784;    // 49 tiles; last chunk 432 = 27 tiles
constexpr float kLog2e = 1.44269504088896340736f;

static __device__ inline unsigned short bf16_rne(float x) {
    unsigned int u = __builtin_bit_cast(unsigned int, x);
    u = (u + 0x7FFFu + ((u >> 16) & 1u)) >> 16;
    return (unsigned short)u;
}
static __device__ inline float bf16_f32(unsigned short h) {
    unsigned int u = ((unsigned int)h) << 16;
    return __builtin_bit_cast(float, u);
}

__global__ __launch_bounds__(256) void prep_e_kernel(
    const float* __restrict__ src, unsigned short* __restrict__ hi,
    unsigned short* __restrict__ lo, int total4, float scale)
{
    int i = blockIdx.x * 256 + threadIdx.x;
    if (i >= total4) return;
    float4 v = ((const float4*)src)[i];
    v.x *= scale; v.y *= scale; v.z *= scale; v.w *= scale;
    ushort4 h, l;
    h.x = bf16_rne(v.x); l.x = bf16_rne(v.x - bf16_f32(h.x));
    h.y = bf16_rne(v.y); l.y = bf16_rne(v.y - bf16_f32(h.y));
    h.z = bf16_rne(v.z); l.z = bf16_rne(v.z - bf16_f32(h.z));
    h.w = bf16_rne(v.w); l.w = bf16_rne(v.w - bf16_f32(h.w));
    ((ushort4*)hi)[i] = h;
    ((ushort4*)lo)[i] = l;
}

#define MFMA16(a, b, c) __builtin_amdgcn_mfma_f32_16x16x32_bf16((a), (b), (c), 0, 0, 0)

__global__ __launch_bounds__(256) void lse_mfma_kernel(
    const unsigned short* __restrict__ Sh,  // [B][64] bf16, pre-scaled log2e
    const unsigned short* __restrict__ Sl,
    const unsigned short* __restrict__ Eh,  // [N][64] bf16
    const unsigned short* __restrict__ El,
    float* __restrict__ part,               // [kChunks][B] exp2-sums
    int N, int Btot)
{
    const int wave = threadIdx.x >> 6;
    const int lane = threadIdx.x & 63;
    const int l15  = lane & 15;
    const int lhi  = lane >> 4;
    const int chunk = blockIdx.x;                 // 0..127
    const int rowg  = blockIdx.y;                 // 0..7
    const int r0 = rowg * 256 + wave * 64;        // wave's first state row

    const int n0 = chunk * kChunkItems;
    const int cnt = min(kChunkItems, N - n0);
    const int ntiles = cnt >> 4;                  // 49 or 27, all full tiles

    // A fragments: [rowtile 0..3][hi/lo][kstep] -> 64 VGPRs
    short8 A[4][2][2];
    #pragma unroll
    for (int rt = 0; rt < 4; ++rt) {
        const int row = r0 + rt * 16 + l15;
        const size_t base = (size_t)row * kD + lhi * 8;
        A[rt][0][0] = *(const short8*)(Sh + base);
        A[rt][0][1] = *(const short8*)(Sh + base + 32);
        A[rt][1][0] = *(const short8*)(Sl + base);
        A[rt][1][1] = *(const short8*)(Sl + base + 32);
    }

    float acc[4][4];
    #pragma unroll
    for (int rt = 0; rt < 4; ++rt)
        #pragma unroll
        for (int j = 0; j < 4; ++j) acc[rt][j] = 0.f;

    const int voff = l15 * kD + lhi * 8;
    const unsigned short* eh = Eh + (size_t)n0 * kD + voff;
    const unsigned short* el = El + (size_t)n0 * kD + voff;

    for (int t = 0; t < ntiles; ++t) {
        const size_t o = (size_t)t * 1024;        // 16 items * 64 dims
        short8 Bh0 = *(const short8*)(eh + o);
        short8 Bh1 = *(const short8*)(eh + o + 32);
        short8 Bl0 = *(const short8*)(el + o);
        short8 Bl1 = *(const short8*)(el + o + 32);

        // 8 independent chains: ca[rt] (hh k0,k1 then hl k0,k1; depth 4),
        //                       cb[rt] (lh k0,k1; depth 2)
        const f32x4 z = {0.f, 0.f, 0.f, 0.f};
        f32x4 ca[4], cb[4];
        #pragma unroll
        for (int rt = 0; rt < 4; ++rt) ca[rt] = MFMA16(A[rt][0][0], Bh0, z);
        #pragma unroll
        for (int rt = 0; rt < 4; ++rt) cb[rt] = MFMA16(A[rt][1][0], Bh0, z);
        #pragma unroll
        for (int rt = 0; rt < 4; ++rt) ca[rt] = MFMA16(A[rt][0][1], Bh1, ca[rt]);
        #pragma unroll
        for (int rt = 0; rt < 4; ++rt) cb[rt] = MFMA16(A[rt][1][1], Bh1, cb[rt]);
        #pragma unroll
        for (int rt = 0; rt < 4; ++rt) ca[rt] = MFMA16(A[rt][0][0], Bl0, ca[rt]);
        #pragma unroll
        for (int rt = 0; rt < 4; ++rt) ca[rt] = MFMA16(A[rt][0][1], Bl1, ca[rt]);

        // C layout: col = lane&15, row = (lane>>4)*4 + j. Accumulate exp2.
        #pragma unroll
        for (int rt = 0; rt < 4; ++rt)
            #pragma unroll
            for (int j = 0; j < 4; ++j)
                acc[rt][j] += __builtin_amdgcn_exp2f(ca[rt][j] + cb[rt][j]);
    }

    // Reduce the 16 column-residues (lanes sharing lhi) per row.
    // part layout [chunk][row]: each block writes 256 contiguous floats.
    #pragma unroll
    for (int rt = 0; rt < 4; ++rt) {
        #pragma unroll
        for (int j = 0; j < 4; ++j) {
            float v = acc[rt][j];
            v += __shfl_xor(v, 1, 64);
            v += __shfl_xor(v, 2, 64);
            v += __shfl_xor(v, 4, 64);
            v += __shfl_xor(v, 8, 64);
            if (l15 == 0) {
                const int row = r0 + rt * 16 + lhi * 4 + j;
                part[(size_t)chunk * Btot + row] = v;
            }
        }
    }
}

__global__ __launch_bounds__(256) void finalize_kernel(
    const float* __restrict__ state,   // original fp32
    const float* __restrict__ emb,
    const int* __restrict__ idx,
    const float* __restrict__ part,    // [kChunks][B]
    float* __restrict__ out, int Btot)
{
    const int wave = threadIdx.x >> 6;
    const int lane = threadIdx.x & 63;
    const int row  = blockIdx.x * 4 + wave;

    // Sum 128 chunk partials (2 per lane), stride Btot between chunks.
    const float* pr = part + row;
    float sv = pr[(size_t)lane * Btot] + pr[(size_t)(lane + 64) * Btot];
    #pragma unroll
    for (int o = 32; o; o >>= 1) sv += __shfl_xor(sv, o, 64);
    float lse = logf(sv);

    // Selected-item logit in fp32: lane k holds dim k.
    int id = idx[row];
    float d = state[(size_t)row * kD + lane] * emb[(size_t)id * kD + lane];
    #pragma unroll
    for (int o = 32; o; o >>= 1) d += __shfl_xor(d, o, 64);

    if (lane == 0) out[row] = d - lse;
}

extern "C" void kernel_launch(void* const* d_in, const int* in_sizes, int n_in,
                              void* d_out, int out_size, void* d_ws, size_t ws_size,
                              hipStream_t stream) {
    const float* state = (const float*)d_in[0];       // [B, 64]
    const int*   idx   = (const int*)d_in[1];         // [B]
    const float* emb   = (const float*)d_in[2];       // [N, 64]
    float*       out   = (float*)d_out;               // [B]

    const int B = in_sizes[0] / kD;                   // 2048
    const int N = in_sizes[2] / kD;                   // 100000

    // Workspace layout (16B-aligned):
    char* ws = (char*)d_ws;
    size_t szE = (size_t)N * kD * sizeof(unsigned short);     // 12.8 MB
    size_t szS = (size_t)B * kD * sizeof(unsigned short);     // 256 KB
    unsigned short* Eh = (unsigned short*)ws;                  ws += szE;
    unsigned short* El = (unsigned short*)ws;                  ws += szE;
    unsigned short* Sh = (unsigned short*)ws;                  ws += szS;
    unsigned short* Sl = (unsigned short*)ws;                  ws += szS;
    float* part = (float*)ws;                                  // 128*B*4 = 1 MB

    // Convert E -> bf16 hi/lo (unscaled); S -> bf16 hi/lo scaled by log2e.
    int e4 = N * kD / 4;
    prep_e_kernel<<<(e4 + 255) / 256, 256, 0, stream>>>(emb, Eh, El, e4, 1.0f);
    int s4 = B * kD / 4;
    prep_e_kernel<<<(s4 + 255) / 256, 256, 0, stream>>>(state, Sh, Sl, s4, kLog2e);

    dim3 grid(kChunks, B / 256);                      // (128, 8) = 1024 blocks
    lse_mfma_kernel<<<grid, 256, 0, stream>>>(Sh, Sl, Eh, El, part, N, B);

    finalize_kernel<<<B / 4, 256, 0, stream>>>(state, emb, idx, part, out, B);
}

// Round 12
// 179.046 us; speedup vs baseline: 1.5838x; 1.1472x over previous
//
#include <hip/hip_runtime.h>
#include <math.h>

// out[b] = dot(state[b], E[idx[b]]) - logsumexp_n dot(state[b], E[n])
// B=2048, D=64, N=100000, T=1.0
//
// Round-12: LDS-staged m97-style structure. Evidence: r9/r11 direct-load
// MFMA is latency-bound (MfmaUtil 20%, VGPR=76 -> compiler never prefetches;
// MFMA-pipe floor ~38us vs 157us measured). global_load_lds queues loads
// without VGPRs; 2-phase double-buffered staging forces load/compute overlap;
// one staged B-tile feeds all 4 waves (4x L1 traffic cut).
// E is prepped into [tile][half][item][dim] with the LDS bank-conflict XOR
// swizzle (byte ^= (item&7)<<4) BAKED INTO THE GLOBAL LAYOUT (rule #21:
// global_load_lds writes linearly; unswizzled reads would be 16-way
// conflicted -- all 16 B-frag lanes hit banks 0-3). Reads apply the same
// XOR via lane-constant offsets.
// Split-precision MFMA: S=Sh+Sl, E=Eh+El, passes hh+lh+hl (~2^-17 rel).
// 125 chunks x 50 tiles = exactly 100000 items, zero tails.
// Block-ID decode puts all 8 rowgroups of a chunk on one XCD (205 KB
// chunk data L2-resident, fetched once per XCD).

typedef short short8 __attribute__((ext_vector_type(8)));
typedef float f32x4 __attribute__((ext_vector_type(4)));

constexpr int kD = 64;
constexpr int kChunks = 125;
constexpr int kTilesPerChunk = 50;   // 125 * 50 * 16 = 100000 exactly
constexpr int kST = 5;               // tiles per stage (20 KB)
constexpr int kStages = 10;          // 50 / 5
constexpr float kLog2e = 1.44269504088896340736f;

static __device__ inline unsigned short bf16_rne(float x) {
    unsigned int u = __builtin_bit_cast(unsigned int, x);
    u = (u + 0x7FFFu + ((u >> 16) & 1u)) >> 16;
    return (unsigned short)u;
}
static __device__ inline float bf16_f32(unsigned short h) {
    unsigned int u = ((unsigned int)h) << 16;
    return __builtin_bit_cast(float, u);
}

// S -> separate Sh/Sl arrays [B][64], scaled by log2e.
__global__ __launch_bounds__(256) void prep_s_kernel(
    const float* __restrict__ src, unsigned short* __restrict__ hi,
    unsigned short* __restrict__ lo, int total4, float scale)
{
    int i = blockIdx.x * 256 + threadIdx.x;
    if (i >= total4) return;
    float4 v = ((const float4*)src)[i];
    v.x *= scale; v.y *= scale; v.z *= scale; v.w *= scale;
    ushort4 h, l;
    h.x = bf16_rne(v.x); l.x = bf16_rne(v.x - bf16_f32(h.x));
    h.y = bf16_rne(v.y); l.y = bf16_rne(v.y - bf16_f32(h.y));
    h.z = bf16_rne(v.z); l.z = bf16_rne(v.z - bf16_f32(h.z));
    h.w = bf16_rne(v.w); l.w = bf16_rne(v.w - bf16_f32(h.w));
    ((ushort4*)hi)[i] = h;
    ((ushort4*)lo)[i] = l;
}

// E -> interleaved [tile][half(hi/lo)][item][dim] bf16, 4 KB per tile,
// with byte offset (within tile, per half) = (item*128 + dq*8) ^ ((item&7)<<4).
__global__ __launch_bounds__(256) void prep_e_kernel(
    const float* __restrict__ src, unsigned short* __restrict__ EhEl, int N)
{
    int i = blockIdx.x * 256 + threadIdx.x;       // one float4 (4 dims) each
    if (i >= N * 16) return;
    int n  = i >> 4;
    int dq = i & 15;
    float4 v = *(const float4*)(src + (size_t)n * kD + dq * 4);
    ushort4 h, l;
    h.x = bf16_rne(v.x); l.x = bf16_rne(v.x - bf16_f32(h.x));
    h.y = bf16_rne(v.y); l.y = bf16_rne(v.y - bf16_f32(h.y));
    h.z = bf16_rne(v.z); l.z = bf16_rne(v.z - bf16_f32(h.z));
    h.w = bf16_rne(v.w); l.w = bf16_rne(v.w - bf16_f32(h.w));
    int tile = n >> 4, item = n & 15;
    unsigned hb = ((unsigned)(item * 128 + dq * 8)) ^ ((unsigned)(item & 7) << 4);
    char* base = (char*)EhEl + (size_t)tile * 4096;
    *(ushort4*)(base + hb)        = h;
    *(ushort4*)(base + 2048 + hb) = l;   // +2048 is bit 11, outside XOR mask
}

#define MFMA16(a, b, c) __builtin_amdgcn_mfma_f32_16x16x32_bf16((a), (b), (c), 0, 0, 0)

__global__ __launch_bounds__(256) void lse_mfma_kernel(
    const unsigned short* __restrict__ Sh,    // [B][64] bf16, scaled log2e
    const unsigned short* __restrict__ Sl,
    const unsigned short* __restrict__ EhEl,  // [6250][2][16][64] swizzled
    float* __restrict__ part,                 // [kChunks][B] exp2-sums
    int Btot)
{
    __shared__ unsigned short lds[2][kST * 2048];   // 2 x 20 KB

    const int tid  = threadIdx.x;
    const int wave = tid >> 6;
    const int lane = tid & 63;
    const int l15  = lane & 15;
    const int lhi  = lane >> 4;

    // bid = xcd + 8*rowg + 64*cgrp : all 8 rowgroups of a chunk share an XCD.
    const int bid  = blockIdx.x;
    const int xcd  = bid & 7;
    const int rowg = (bid >> 3) & 7;
    const int chunk = (bid >> 6) * 8 + xcd;
    if (chunk >= kChunks) return;                 // hole block (24 of 1024)

    const int r0 = rowg * 256 + wave * 64;        // wave's first state row

    // A fragments: [rowtile 0..3][hi/lo][kstep] -> 64 VGPRs
    short8 A[4][2][2];
    #pragma unroll
    for (int rt = 0; rt < 4; ++rt) {
        const int row = r0 + rt * 16 + l15;
        const size_t base = (size_t)row * kD + lhi * 8;
        A[rt][0][0] = *(const short8*)(Sh + base);
        A[rt][0][1] = *(const short8*)(Sh + base + 32);
        A[rt][1][0] = *(const short8*)(Sl + base);
        A[rt][1][1] = *(const short8*)(Sl + base + 32);
    }

    float acc[4][4];
    #pragma unroll
    for (int rt = 0; rt < 4; ++rt)
        #pragma unroll
        for (int j = 0; j < 4; ++j) acc[rt][j] = 0.f;

    // Swizzled lane-constant LDS read offsets (bytes within a tile half).
    const unsigned xorv = (unsigned)((l15 & 7) << 4);
    const int o_h0 = (int)(((unsigned)(l15 * 128 + lhi * 16))      ^ xorv);
    const int o_h1 = (int)(((unsigned)(l15 * 128 + lhi * 16 + 64)) ^ xorv);

    const unsigned short* src = EhEl + (size_t)chunk * kTilesPerChunk * 2048;

    // Stage s (5 tiles = 10240 elems = 20 KB) into lds[buf].
#define STAGE(buf, s) { \
    const unsigned short* sp_ = src + (size_t)(s) * (kST * 2048); \
    _Pragma("unroll") \
    for (int c = 0; c < kST; ++c) { \
        __builtin_amdgcn_global_load_lds( \
            (const __attribute__((address_space(1))) void*)(sp_ + (size_t)(c * 256 + tid) * 8), \
            (__attribute__((address_space(3))) void*)&lds[buf][(c * 256 + wave * 64) * 8], \
            16, 0, 0); \
    } }

    STAGE(0, 0);
    __syncthreads();                      // stage 0 resident

    for (int s = 0; s < kStages; ++s) {
        const int cur = s & 1;
        if (s + 1 < kStages) STAGE(cur ^ 1, s + 1);   // async prefetch

        const char* lb = (const char*)lds[cur];
        #pragma unroll
        for (int tt = 0; tt < kST; ++tt) {
            const char* tp = lb + tt * 4096;
            short8 Bh0 = *(const short8*)(tp + o_h0);
            short8 Bh1 = *(const short8*)(tp + o_h1);
            short8 Bl0 = *(const short8*)(tp + 2048 + o_h0);
            short8 Bl1 = *(const short8*)(tp + 2048 + o_h1);

            const f32x4 z = {0.f, 0.f, 0.f, 0.f};
            f32x4 ca[4], cb[4];
            #pragma unroll
            for (int rt = 0; rt < 4; ++rt) ca[rt] = MFMA16(A[rt][0][0], Bh0, z);
            #pragma unroll
            for (int rt = 0; rt < 4; ++rt) cb[rt] = MFMA16(A[rt][1][0], Bh0, z);
            #pragma unroll
            for (int rt = 0; rt < 4; ++rt) ca[rt] = MFMA16(A[rt][0][1], Bh1, ca[rt]);
            #pragma unroll
            for (int rt = 0; rt < 4; ++rt) cb[rt] = MFMA16(A[rt][1][1], Bh1, cb[rt]);
            #pragma unroll
            for (int rt = 0; rt < 4; ++rt) ca[rt] = MFMA16(A[rt][0][0], Bl0, ca[rt]);
            #pragma unroll
            for (int rt = 0; rt < 4; ++rt) ca[rt] = MFMA16(A[rt][0][1], Bl1, ca[rt]);

            // C layout: col = lane&15, row = (lane>>4)*4 + j.
            #pragma unroll
            for (int rt = 0; rt < 4; ++rt)
                #pragma unroll
                for (int j = 0; j < 4; ++j)
                    acc[rt][j] += __builtin_amdgcn_exp2f(ca[rt][j] + cb[rt][j]);
        }
        __syncthreads();   // drains vmcnt (stage s+1 ready) + readers done
    }
#undef STAGE

    // Reduce 16 column-residues (lanes sharing lhi) per row; write part.
    #pragma unroll
    for (int rt = 0; rt < 4; ++rt) {
        #pragma unroll
        for (int j = 0; j < 4; ++j) {
            float v = acc[rt][j];
            v += __shfl_xor(v, 1, 64);
            v += __shfl_xor(v, 2, 64);
            v += __shfl_xor(v, 4, 64);
            v += __shfl_xor(v, 8, 64);
            if (l15 == 0) {
                const int row = r0 + rt * 16 + lhi * 4 + j;
                part[(size_t)chunk * Btot + row] = v;
            }
        }
    }
}

__global__ __launch_bounds__(256) void finalize_kernel(
    const float* __restrict__ state,   // original fp32
    const float* __restrict__ emb,
    const int* __restrict__ idx,
    const float* __restrict__ part,    // [kChunks][B]
    float* __restrict__ out, int Btot)
{
    const int wave = threadIdx.x >> 6;
    const int lane = threadIdx.x & 63;
    const int row  = blockIdx.x * 4 + wave;

    const float* pr = part + row;
    float sv = 0.f;
    if (lane < kChunks)      sv += pr[(size_t)lane * Btot];
    if (lane + 64 < kChunks) sv += pr[(size_t)(lane + 64) * Btot];
    #pragma unroll
    for (int o = 32; o; o >>= 1) sv += __shfl_xor(sv, o, 64);
    float lse = logf(sv);

    // Selected-item logit in fp32: lane k holds dim k.
    int id = idx[row];
    float d = state[(size_t)row * kD + lane] * emb[(size_t)id * kD + lane];
    #pragma unroll
    for (int o = 32; o; o >>= 1) d += __shfl_xor(d, o, 64);

    if (lane == 0) out[row] = d - lse;
}

extern "C" void kernel_launch(void* const* d_in, const int* in_sizes, int n_in,
                              void* d_out, int out_size, void* d_ws, size_t ws_size,
                              hipStream_t stream) {
    const float* state = (const float*)d_in[0];       // [B, 64]
    const int*   idx   = (const int*)d_in[1];         // [B]
    const float* emb   = (const float*)d_in[2];       // [N, 64]
    float*       out   = (float*)d_out;               // [B]

    const int B = in_sizes[0] / kD;                   // 2048
    const int N = in_sizes[2] / kD;                   // 100000

    // Workspace layout (16B-aligned):
    char* ws = (char*)d_ws;
    size_t szE = (size_t)N * kD * 2 * sizeof(unsigned short); // 25.6 MB (hi+lo)
    size_t szS = (size_t)B * kD * sizeof(unsigned short);     // 256 KB
    unsigned short* EhEl = (unsigned short*)ws;                ws += szE;
    unsigned short* Sh   = (unsigned short*)ws;                ws += szS;
    unsigned short* Sl   = (unsigned short*)ws;                ws += szS;
    float* part = (float*)ws;                                  // 125*B*4 = 1 MB

    prep_e_kernel<<<(N * 16 + 255) / 256, 256, 0, stream>>>(emb, EhEl, N);
    int s4 = B * kD / 4;
    prep_s_kernel<<<(s4 + 255) / 256, 256, 0, stream>>>(state, Sh, Sl, s4, kLog2e);

    lse_mfma_kernel<<<1024, 256, 0, stream>>>(Sh, Sl, EhEl, part, B);

    finalize_kernel<<<B / 4, 256, 0, stream>>>(state, emb, idx, part, out, B);
}